// Round 10
// baseline (75.306 us; speedup 1.0000x reference)
//
#include <hip/hip_runtime.h>

#define N_NODES 50000
#define N_EDGES 800000
#define D_FEAT 64

// dst bucket sort: bucket = dst>>5 (32 nodes/bucket), 1563 used of 2048
#define NBINS 2048
#define BSORT 400                                    // sort blocks; N_EDGES/BSORT = 2000 exact
#define SORT_CHUNK (N_EDGES / BSORT)                 // 2000
#define NSCAN (NBINS * BSORT)                        // 819200 = 800*1024 exact
#define SCAN_BLOCK 1024
#define SCAN_BLOCKS (NSCAN / SCAN_BLOCK)             // 800
#define AGG_CAP 4096
#define NAGG ((N_NODES + 31) / 32)                   // 1563 buckets

// out-degree histogram: single pass, u8x4-packed LDS counters
#define HCHUNKS 64
#define HCHUNK (N_EDGES / HCHUNKS)                   // 12500 exact
#define HWORDS ((N_NODES + 3) / 4)                   // 12500 u32 = 50 KB LDS

#define RS_BLOCKS ((N_NODES + 255) / 256)            // 196

// ---------- Kernel 1 (fused): src out-degree histogram  ||  dst bucket counts ----------
__global__ __launch_bounds__(256)
void hist_count_kernel(const int* __restrict__ src, const int* __restrict__ dst,
                       unsigned int* __restrict__ hp32, unsigned int* __restrict__ gh) {
    __shared__ unsigned int lh[HWORDS];  // 50 KB; count path uses first NBINS words
    const int b = blockIdx.x, t = threadIdx.x;
    if (b < HCHUNKS) {
        for (int i = t; i < HWORDS; i += 256) lh[i] = 0u;
        __syncthreads();
        const int4* s4 = (const int4*)(src + b * HCHUNK);
        for (int i = t; i < HCHUNK / 4; i += 256) {
            int4 v = s4[i];
            atomicAdd(&lh[v.x >> 2], 1u << ((v.x & 3) * 8));
            atomicAdd(&lh[v.y >> 2], 1u << ((v.y & 3) * 8));
            atomicAdd(&lh[v.z >> 2], 1u << ((v.z & 3) * 8));
            atomicAdd(&lh[v.w >> 2], 1u << ((v.w & 3) * 8));
        }
        __syncthreads();
        for (int w = t; w < HWORDS; w += 256)
            hp32[(size_t)b * HWORDS + w] = lh[w];
    } else {
        const int cb = b - HCHUNKS;
        for (int i = t; i < NBINS; i += 256) lh[i] = 0;
        __syncthreads();
        const int4* d4 = (const int4*)(dst + cb * SORT_CHUNK);
        for (int i = t; i < SORT_CHUNK / 4; i += 256) {
            int4 v = d4[i];
            atomicAdd(&lh[v.x >> 5], 1u);
            atomicAdd(&lh[v.y >> 5], 1u);
            atomicAdd(&lh[v.z >> 5], 1u);
            atomicAdd(&lh[v.w >> 5], 1u);
        }
        __syncthreads();
        for (int i = t; i < NBINS; i += 256) gh[(size_t)i * BSORT + cb] = lh[i];  // bin-major
    }
}

// ---------- Kernel 2 (fused): scan block-reduce  ||  degree merge + rs ----------
__global__ __launch_bounds__(SCAN_BLOCK)
void scanred_rs_kernel(const unsigned int* __restrict__ gh, unsigned int* __restrict__ partial,
                       const unsigned char* __restrict__ hp8, float* __restrict__ rs) {
    const int b = blockIdx.x;
    if (b < SCAN_BLOCKS) {
        __shared__ unsigned int wsum[SCAN_BLOCK / 64];
        int g = b * SCAN_BLOCK + threadIdx.x;
        unsigned int v = gh[g];
        for (int off = 32; off > 0; off >>= 1) v += __shfl_down(v, off, 64);
        if ((threadIdx.x & 63) == 0) wsum[threadIdx.x >> 6] = v;
        __syncthreads();
        if (threadIdx.x < SCAN_BLOCK / 64) {
            unsigned int s = wsum[threadIdx.x];
            for (int off = SCAN_BLOCK / 128; off > 0; off >>= 1) s += __shfl_down(s, off, 64);
            if (threadIdx.x == 0) partial[b] = s;
        }
    } else {
        if (threadIdx.x < 256) {
            int v = (b - SCAN_BLOCKS) * 256 + threadIdx.x;
            if (v < N_NODES) {
                unsigned int s = 0;
                #pragma unroll
                for (int c = 0; c < HCHUNKS; ++c) s += hp8[(size_t)c * (HWORDS * 4) + v];
                rs[v] = rsqrtf((float)s);
            }
        }
    }
}

// ---------- Kernel 3: scan finalize (in-LDS re-scan of the 800 partials) ----------
__global__ __launch_bounds__(SCAN_BLOCK)
void scan_final_kernel(unsigned int* __restrict__ data, const unsigned int* __restrict__ partial) {
    __shared__ unsigned int arr[SCAN_BLOCK];
    __shared__ unsigned int pbase[SCAN_BLOCK];
    const int t = threadIdx.x;
    const int g = blockIdx.x * SCAN_BLOCK + t;
    pbase[t] = (t < SCAN_BLOCKS) ? partial[t] : 0u;
    __syncthreads();
    for (int off = 1; off < SCAN_BLOCK; off <<= 1) {
        unsigned int u = (t >= off) ? pbase[t - off] : 0u;
        __syncthreads();
        pbase[t] += u;
        __syncthreads();
    }
    const unsigned int base = (blockIdx.x == 0) ? 0u : pbase[blockIdx.x - 1];
    unsigned int v = data[g];
    arr[t] = v;
    __syncthreads();
    for (int off = 1; off < SCAN_BLOCK; off <<= 1) {
        unsigned int u = (t >= off) ? arr[t - off] : 0u;
        __syncthreads();
        arr[t] += u;
        __syncthreads();
    }
    data[g] = base + arr[t] - v;  // exclusive, in-place
}

// ---------- Kernel 4: scatter keys into buckets via LDS cursors (plain stores) ----------
__global__ __launch_bounds__(256)
void bucket_scatter_kernel(const int* __restrict__ src, const int* __restrict__ dst,
                           const unsigned int* __restrict__ gh, unsigned int* __restrict__ keysB) {
    __shared__ unsigned int cur[NBINS];  // 8 KB
    const int b = blockIdx.x, t = threadIdx.x;
    for (int i = t; i < NBINS; i += 256) cur[i] = gh[(size_t)i * BSORT + b];
    __syncthreads();
    const int4* s4 = (const int4*)(src + b * SORT_CHUNK);
    const int4* d4 = (const int4*)(dst + b * SORT_CHUNK);
    for (int i = t; i < SORT_CHUNK / 4; i += 256) {
        int4 s = s4[i];
        int4 d = d4[i];
        unsigned int p0 = atomicAdd(&cur[d.x >> 5], 1u);
        keysB[p0] = ((unsigned int)d.x << 16) | (unsigned int)s.x;
        unsigned int p1 = atomicAdd(&cur[d.y >> 5], 1u);
        keysB[p1] = ((unsigned int)d.y << 16) | (unsigned int)s.y;
        unsigned int p2 = atomicAdd(&cur[d.z >> 5], 1u);
        keysB[p2] = ((unsigned int)d.z << 16) | (unsigned int)s.z;
        unsigned int p3 = atomicAdd(&cur[d.w >> 5], 1u);
        keysB[p3] = ((unsigned int)d.w << 16) | (unsigned int)s.w;
    }
}

// ---------- Kernel 5: block per bucket (32 nodes): LDS counting-sort + wave-per-node gather ----------
__global__ __launch_bounds__(256)
void bucket_aggregate_kernel(const float* __restrict__ x, const unsigned int* __restrict__ gh,
                             const unsigned int* __restrict__ keysB, const float* __restrict__ rs,
                             float* __restrict__ h) {
    __shared__ unsigned int ebuf[AGG_CAP];  // 16 KB
    __shared__ unsigned int ecnt[32];
    __shared__ unsigned int eoff[33];
    const int g = blockIdx.x;
    const int t = threadIdx.x;
    const int lane = t & 63;
    const int w = t >> 6;
    const unsigned int base = gh[(size_t)g * BSORT];
    const unsigned int end  = gh[(size_t)(g + 1) * BSORT];
    const int cnt = (int)(end - base);

    if (cnt > 0 && cnt <= AGG_CAP) {  // block-uniform branch
        if (t < 32) ecnt[t] = 0;
        __syncthreads();
        for (int i = t; i < cnt; i += 256) atomicAdd(&ecnt[(keysB[base + i] >> 16) & 31], 1u);
        __syncthreads();
        if (t == 0) {
            unsigned int r = 0;
            for (int k2 = 0; k2 < 32; ++k2) { eoff[k2] = r; r += ecnt[k2]; }
            eoff[32] = r;
        }
        __syncthreads();
        if (t < 32) ecnt[t] = eoff[t];  // reuse as cursors
        __syncthreads();
        for (int i = t; i < cnt; i += 256) {
            unsigned int k = keysB[base + i];
            ebuf[atomicAdd(&ecnt[(k >> 16) & 31], 1u)] = k;
        }
        __syncthreads();
        for (int nl = w; nl < 32; nl += 4) {
            int node = g * 32 + nl;
            if (node >= N_NODES) continue;
            int jb = (int)eoff[nl], je = (int)eoff[nl + 1];
            float acc = 0.0f;
            int j = jb;
            // 8-deep: keep 8 gathers in flight per wave to cover L2/L3 latency
            for (; j + 7 < je; j += 8) {
                unsigned int s0 = ebuf[j] & 0xFFFFu,     s1 = ebuf[j + 1] & 0xFFFFu;
                unsigned int s2 = ebuf[j + 2] & 0xFFFFu, s3 = ebuf[j + 3] & 0xFFFFu;
                unsigned int s4 = ebuf[j + 4] & 0xFFFFu, s5 = ebuf[j + 5] & 0xFFFFu;
                unsigned int s6 = ebuf[j + 6] & 0xFFFFu, s7 = ebuf[j + 7] & 0xFFFFu;
                float v0 = x[(size_t)s0 * D_FEAT + lane];
                float v1 = x[(size_t)s1 * D_FEAT + lane];
                float v2 = x[(size_t)s2 * D_FEAT + lane];
                float v3 = x[(size_t)s3 * D_FEAT + lane];
                float v4 = x[(size_t)s4 * D_FEAT + lane];
                float v5 = x[(size_t)s5 * D_FEAT + lane];
                float v6 = x[(size_t)s6 * D_FEAT + lane];
                float v7 = x[(size_t)s7 * D_FEAT + lane];
                float w0 = rs[s0], w1 = rs[s1], w2 = rs[s2], w3 = rs[s3];
                float w4 = rs[s4], w5 = rs[s5], w6 = rs[s6], w7 = rs[s7];
                acc = fmaf(v0, w0, acc); acc = fmaf(v1, w1, acc);
                acc = fmaf(v2, w2, acc); acc = fmaf(v3, w3, acc);
                acc = fmaf(v4, w4, acc); acc = fmaf(v5, w5, acc);
                acc = fmaf(v6, w6, acc); acc = fmaf(v7, w7, acc);
            }
            for (; j + 3 < je; j += 4) {
                unsigned int s0 = ebuf[j] & 0xFFFFu,     s1 = ebuf[j + 1] & 0xFFFFu;
                unsigned int s2 = ebuf[j + 2] & 0xFFFFu, s3 = ebuf[j + 3] & 0xFFFFu;
                float v0 = x[(size_t)s0 * D_FEAT + lane];
                float v1 = x[(size_t)s1 * D_FEAT + lane];
                float v2 = x[(size_t)s2 * D_FEAT + lane];
                float v3 = x[(size_t)s3 * D_FEAT + lane];
                float w0 = rs[s0], w1 = rs[s1], w2 = rs[s2], w3 = rs[s3];
                acc = fmaf(v0, w0, acc); acc = fmaf(v1, w1, acc);
                acc = fmaf(v2, w2, acc); acc = fmaf(v3, w3, acc);
            }
            for (; j < je; ++j) {
                unsigned int s = ebuf[j] & 0xFFFFu;
                acc = fmaf(x[(size_t)s * D_FEAT + lane], rs[s], acc);
            }
            h[(size_t)node * D_FEAT + lane] = (je > jb) ? acc * rs[node] : 0.0f;
        }
    } else {
        // cnt == 0 (write zeros) or pathological overflow: filter directly from global.
        for (int nl = w; nl < 32; nl += 4) {
            int node = g * 32 + nl;
            if (node >= N_NODES) continue;
            float acc = 0.0f;
            int any = 0;
            for (unsigned int j = base; j < end; ++j) {
                unsigned int k = keysB[j];
                if ((int)((k >> 16) & 31) == nl) {
                    unsigned int s = k & 0xFFFFu;
                    acc = fmaf(x[(size_t)s * D_FEAT + lane], rs[s], acc);
                    any = 1;
                }
            }
            h[(size_t)node * D_FEAT + lane] = any ? acc * rs[node] : 0.0f;
        }
    }
}

// ---------- Fallback (tiny ws): atomic scatter ----------
__global__ void fb_degree_kernel(const int* __restrict__ src, unsigned int* __restrict__ deg,
                                 int n_edges) {
    int i = blockIdx.x * blockDim.x + threadIdx.x;
    int stride = gridDim.x * blockDim.x;
    for (; i < n_edges; i += stride) atomicAdd(&deg[src[i]], 1u);
}
__global__ void fb_scatter_kernel(const float* __restrict__ x, const int* __restrict__ src,
                                  const int* __restrict__ dst, const unsigned int* __restrict__ deg,
                                  float* __restrict__ h, int n_edges) {
    const int lane = threadIdx.x & 63;
    const int wave = (int)((blockIdx.x * blockDim.x + threadIdx.x) >> 6);
    const int nwaves = (int)((gridDim.x * blockDim.x) >> 6);
    for (int e = wave; e < n_edges; e += nwaves) {
        int s = __builtin_amdgcn_readfirstlane(src[e]);
        int d = __builtin_amdgcn_readfirstlane(dst[e]);
        float norm = rsqrtf((float)deg[s] * (float)deg[d]);
        atomicAdd(&h[d * D_FEAT + lane], x[s * D_FEAT + lane] * norm);
    }
}

// ---------- launch ----------
extern "C" void kernel_launch(void* const* d_in, const int* in_sizes, int n_in,
                              void* d_out, int out_size, void* d_ws, size_t ws_size,
                              hipStream_t stream) {
    const float* x   = (const float*)d_in[0];
    const int*   src = (const int*)d_in[1];
    const int*   dst = (const int*)d_in[2];
    float* h = (float*)d_out;

    // Workspace layout (~6.7 MB; rounds 1-2 proved >= 7.2 MB available):
    //   keysB : N_EDGES u32 (3.2 MB) -- aliased with hp32 (64*12500 u32 = 3.2 MB);
    //           hp32 fully consumed by scanred_rs before bucket_scatter writes keysB.
    //   gh    : NSCAN u32 (3.28 MB)
    //   rs    : N_NODES f32 (200 KB)
    //   spart : 1024 u32
    size_t off = 0;
    unsigned int*  keysB = (unsigned int*)((char*)d_ws + off);  off += (size_t)N_EDGES * 4;
    unsigned int*  hp32  = keysB;
    unsigned int*  gh    = (unsigned int*)((char*)d_ws + off);  off += (size_t)NSCAN * 4;
    float*         rs    = (float*)((char*)d_ws + off);         off += (size_t)N_NODES * 4;
    unsigned int*  spart = (unsigned int*)((char*)d_ws + off);  off += 1024 * 4;

    if (ws_size >= off) {
        // No memsets: every workspace/output element is fully overwritten.
        hist_count_kernel<<<dim3(HCHUNKS + BSORT), dim3(256), 0, stream>>>(src, dst, hp32, gh);
        scanred_rs_kernel<<<dim3(SCAN_BLOCKS + RS_BLOCKS), dim3(SCAN_BLOCK), 0, stream>>>(
            gh, spart, (const unsigned char*)hp32, rs);
        scan_final_kernel<<<dim3(SCAN_BLOCKS), dim3(SCAN_BLOCK), 0, stream>>>(gh, spart);
        bucket_scatter_kernel<<<dim3(BSORT), dim3(256), 0, stream>>>(src, dst, gh, keysB);
        bucket_aggregate_kernel<<<dim3(NAGG), dim3(256), 0, stream>>>(x, gh, keysB, rs, h);
    } else {
        // Fallback: atomic scatter (any ws >= 200 KB).
        unsigned int* deg = (unsigned int*)d_ws;
        hipMemsetAsync(deg, 0, N_NODES * sizeof(unsigned int), stream);
        hipMemsetAsync(d_out, 0, (size_t)out_size * sizeof(float), stream);
        fb_degree_kernel<<<dim3(1024), dim3(256), 0, stream>>>(src, deg, N_EDGES);
        fb_scatter_kernel<<<dim3(2048), dim3(256), 0, stream>>>(x, src, dst, deg, h, N_EDGES);
    }
}

// Round 11
// 62.519 us; speedup vs baseline: 1.2045x; 1.2045x over previous
//
#include <hip/hip_runtime.h>

#define N_NODES 50000
#define N_EDGES 800000
#define D_FEAT 64

// dst bucket sort: bucket = dst>>5 (32 nodes/bucket), 1563 used of 2048
#define NBINS 2048
#define BSORT 100                                    // sort blocks; N_EDGES/BSORT = 8000 exact
#define SORT_CHUNK (N_EDGES / BSORT)                 // 8000
#define NSCAN (NBINS * BSORT)                        // 204800 = 200*1024 exact
#define SCAN_BLOCK 1024
#define SCAN_BLOCKS (NSCAN / SCAN_BLOCK)             // 200
#define AGG_CAP 4096
#define NAGG ((N_NODES + 31) / 32)                   // 1563 buckets

// out-degree histogram: single pass, u8x4-packed LDS counters
#define HCHUNKS 64
#define HCHUNK (N_EDGES / HCHUNKS)                   // 12500 exact
#define HWORDS ((N_NODES + 3) / 4)                   // 12500 u32 = 50 KB LDS

#define RS_BLOCKS ((N_NODES + 255) / 256)            // 196

// ---------- Kernel 1 (fused): src out-degree histogram  ||  dst bucket counts ----------
__global__ __launch_bounds__(256)
void hist_count_kernel(const int* __restrict__ src, const int* __restrict__ dst,
                       unsigned int* __restrict__ hp32, unsigned int* __restrict__ gh) {
    __shared__ unsigned int lh[HWORDS];  // 50 KB; count path uses first NBINS words
    const int b = blockIdx.x, t = threadIdx.x;
    if (b < HCHUNKS) {
        for (int i = t; i < HWORDS; i += 256) lh[i] = 0u;
        __syncthreads();
        const int4* s4 = (const int4*)(src + b * HCHUNK);
        for (int i = t; i < HCHUNK / 4; i += 256) {
            int4 v = s4[i];
            atomicAdd(&lh[v.x >> 2], 1u << ((v.x & 3) * 8));
            atomicAdd(&lh[v.y >> 2], 1u << ((v.y & 3) * 8));
            atomicAdd(&lh[v.z >> 2], 1u << ((v.z & 3) * 8));
            atomicAdd(&lh[v.w >> 2], 1u << ((v.w & 3) * 8));
        }
        __syncthreads();
        for (int w = t; w < HWORDS; w += 256)
            hp32[(size_t)b * HWORDS + w] = lh[w];
    } else {
        const int cb = b - HCHUNKS;
        for (int i = t; i < NBINS; i += 256) lh[i] = 0;
        __syncthreads();
        const int4* d4 = (const int4*)(dst + cb * SORT_CHUNK);
        for (int i = t; i < SORT_CHUNK / 4; i += 256) {
            int4 v = d4[i];
            atomicAdd(&lh[v.x >> 5], 1u);
            atomicAdd(&lh[v.y >> 5], 1u);
            atomicAdd(&lh[v.z >> 5], 1u);
            atomicAdd(&lh[v.w >> 5], 1u);
        }
        __syncthreads();
        for (int i = t; i < NBINS; i += 256) gh[(size_t)i * BSORT + cb] = lh[i];  // bin-major
    }
}

// ---------- Kernel 2 (fused): scan block-reduce  ||  degree merge + rs ----------
__global__ __launch_bounds__(SCAN_BLOCK)
void scanred_rs_kernel(const unsigned int* __restrict__ gh, unsigned int* __restrict__ partial,
                       const unsigned char* __restrict__ hp8, float* __restrict__ rs) {
    const int b = blockIdx.x;
    if (b < SCAN_BLOCKS) {
        __shared__ unsigned int wsum[SCAN_BLOCK / 64];
        int g = b * SCAN_BLOCK + threadIdx.x;
        unsigned int v = gh[g];
        for (int off = 32; off > 0; off >>= 1) v += __shfl_down(v, off, 64);
        if ((threadIdx.x & 63) == 0) wsum[threadIdx.x >> 6] = v;
        __syncthreads();
        if (threadIdx.x < SCAN_BLOCK / 64) {
            unsigned int s = wsum[threadIdx.x];
            for (int off = SCAN_BLOCK / 128; off > 0; off >>= 1) s += __shfl_down(s, off, 64);
            if (threadIdx.x == 0) partial[b] = s;
        }
    } else {
        if (threadIdx.x < 256) {
            int v = (b - SCAN_BLOCKS) * 256 + threadIdx.x;
            if (v < N_NODES) {
                unsigned int s = 0;
                #pragma unroll
                for (int c = 0; c < HCHUNKS; ++c) s += hp8[(size_t)c * (HWORDS * 4) + v];
                rs[v] = rsqrtf((float)s);
            }
        }
    }
}

// ---------- Kernel 3: scan finalize (in-LDS re-scan of the 200 partials) ----------
__global__ __launch_bounds__(SCAN_BLOCK)
void scan_final_kernel(unsigned int* __restrict__ data, const unsigned int* __restrict__ partial) {
    __shared__ unsigned int arr[SCAN_BLOCK];
    __shared__ unsigned int pbase[256];
    const int t = threadIdx.x;
    const int g = blockIdx.x * SCAN_BLOCK + t;
    if (t < 256) pbase[t] = (t < SCAN_BLOCKS) ? partial[t] : 0u;
    __syncthreads();
    for (int off = 1; off < 256; off <<= 1) {
        unsigned int u = (t < 256 && t >= off) ? pbase[t - off] : 0u;
        __syncthreads();
        if (t < 256 && t >= off) pbase[t] += u;
        __syncthreads();
    }
    const unsigned int base = (blockIdx.x == 0) ? 0u : pbase[blockIdx.x - 1];
    unsigned int v = data[g];
    arr[t] = v;
    __syncthreads();
    for (int off = 1; off < SCAN_BLOCK; off <<= 1) {
        unsigned int u = (t >= off) ? arr[t - off] : 0u;
        __syncthreads();
        arr[t] += u;
        __syncthreads();
    }
    data[g] = base + arr[t] - v;  // exclusive, in-place
}

// ---------- Kernel 4: scatter keys via LDS cursors; 1024 threads for 4x TLP ----------
__global__ __launch_bounds__(1024)
void bucket_scatter_kernel(const int* __restrict__ src, const int* __restrict__ dst,
                           const unsigned int* __restrict__ gh, unsigned int* __restrict__ keysB) {
    __shared__ unsigned int cur[NBINS];  // 8 KB
    const int b = blockIdx.x, t = threadIdx.x;
    for (int i = t; i < NBINS; i += 1024) cur[i] = gh[(size_t)i * BSORT + b];
    __syncthreads();
    const int4* s4 = (const int4*)(src + b * SORT_CHUNK);
    const int4* d4 = (const int4*)(dst + b * SORT_CHUNK);
    for (int i = t; i < SORT_CHUNK / 4; i += 1024) {
        int4 s = s4[i];
        int4 d = d4[i];
        unsigned int p0 = atomicAdd(&cur[d.x >> 5], 1u);
        keysB[p0] = ((unsigned int)d.x << 16) | (unsigned int)s.x;
        unsigned int p1 = atomicAdd(&cur[d.y >> 5], 1u);
        keysB[p1] = ((unsigned int)d.y << 16) | (unsigned int)s.y;
        unsigned int p2 = atomicAdd(&cur[d.z >> 5], 1u);
        keysB[p2] = ((unsigned int)d.z << 16) | (unsigned int)s.z;
        unsigned int p3 = atomicAdd(&cur[d.w >> 5], 1u);
        keysB[p3] = ((unsigned int)d.w << 16) | (unsigned int)s.w;
    }
}

// ---------- Kernel 5: block per bucket: counting-sort + float4 gather (4 edges/instr) ----------
__global__ __launch_bounds__(256)
void bucket_aggregate_kernel(const float* __restrict__ x, const unsigned int* __restrict__ gh,
                             const unsigned int* __restrict__ keysB, const float* __restrict__ rs,
                             float* __restrict__ h) {
    __shared__ unsigned int ebuf[AGG_CAP];  // 16 KB
    __shared__ unsigned int ecnt[32];
    __shared__ unsigned int eoff[33];
    const int g = blockIdx.x;
    const int t = threadIdx.x;
    const int lane = t & 63;
    const int w = t >> 6;
    const unsigned int base = gh[(size_t)g * BSORT];
    const unsigned int end  = gh[(size_t)(g + 1) * BSORT];
    const int cnt = (int)(end - base);

    if (cnt > 0 && cnt <= AGG_CAP) {  // block-uniform branch
        if (t < 32) ecnt[t] = 0;
        __syncthreads();
        for (int i = t; i < cnt; i += 256) atomicAdd(&ecnt[(keysB[base + i] >> 16) & 31], 1u);
        __syncthreads();
        if (t == 0) {
            unsigned int r = 0;
            for (int k2 = 0; k2 < 32; ++k2) { eoff[k2] = r; r += ecnt[k2]; }
            eoff[32] = r;
        }
        __syncthreads();
        if (t < 32) ecnt[t] = eoff[t];  // reuse as cursors
        __syncthreads();
        for (int i = t; i < cnt; i += 256) {
            unsigned int k = keysB[base + i];
            ebuf[atomicAdd(&ecnt[(k >> 16) & 31], 1u)] = k;
        }
        __syncthreads();

        const int grp = lane >> 4;   // edge sub-group 0..3
        const int fl  = lane & 15;   // float4 slot within the 64-feature row
        for (int nl = w; nl < 32; nl += 4) {
            int node = g * 32 + nl;
            if (node >= N_NODES) continue;
            const int jb = (int)eoff[nl];
            const int m  = (int)eoff[nl + 1] - jb;
            float ax = 0.0f, ay = 0.0f, az = 0.0f, aw = 0.0f;
            int jj = 0;
            // main: 8 edges per iteration (2 x dwordx4 in flight per wave)
            for (; jj + 8 <= m; jj += 8) {
                unsigned int s0 = ebuf[jb + jj + grp] & 0xFFFFu;
                unsigned int s1 = ebuf[jb + jj + 4 + grp] & 0xFFFFu;
                const float4 v0 = *(const float4*)&x[(size_t)s0 * D_FEAT + fl * 4];
                const float4 v1 = *(const float4*)&x[(size_t)s1 * D_FEAT + fl * 4];
                float w0 = rs[s0], w1 = rs[s1];
                ax = fmaf(v0.x, w0, ax); ay = fmaf(v0.y, w0, ay);
                az = fmaf(v0.z, w0, az); aw = fmaf(v0.w, w0, aw);
                ax = fmaf(v1.x, w1, ax); ay = fmaf(v1.y, w1, ay);
                az = fmaf(v1.z, w1, az); aw = fmaf(v1.w, w1, aw);
            }
            // tail: up to 7 edges, two masked groups-of-4
            if (jj < m) {
                int idx = jj + grp;
                unsigned int s = ebuf[jb + min(idx, m - 1)] & 0xFFFFu;
                float wgt = (idx < m) ? rs[s] : 0.0f;
                const float4 v = *(const float4*)&x[(size_t)s * D_FEAT + fl * 4];
                ax = fmaf(v.x, wgt, ax); ay = fmaf(v.y, wgt, ay);
                az = fmaf(v.z, wgt, az); aw = fmaf(v.w, wgt, aw);
                jj += 4;
                if (jj < m) {
                    idx = jj + grp;
                    unsigned int s2 = ebuf[jb + min(idx, m - 1)] & 0xFFFFu;
                    float wgt2 = (idx < m) ? rs[s2] : 0.0f;
                    const float4 v2 = *(const float4*)&x[(size_t)s2 * D_FEAT + fl * 4];
                    ax = fmaf(v2.x, wgt2, ax); ay = fmaf(v2.y, wgt2, ay);
                    az = fmaf(v2.z, wgt2, az); aw = fmaf(v2.w, wgt2, aw);
                }
            }
            // combine the 4 edge sub-groups: lanes l, l^16, l^32
            ax += __shfl_xor(ax, 16, 64); ay += __shfl_xor(ay, 16, 64);
            az += __shfl_xor(az, 16, 64); aw += __shfl_xor(aw, 16, 64);
            ax += __shfl_xor(ax, 32, 64); ay += __shfl_xor(ay, 32, 64);
            az += __shfl_xor(az, 32, 64); aw += __shfl_xor(aw, 32, 64);
            if (lane < 16) {
                float4 o;
                if (m > 0) {
                    const float rsn = rs[node];
                    o.x = ax * rsn; o.y = ay * rsn; o.z = az * rsn; o.w = aw * rsn;
                } else {
                    o.x = o.y = o.z = o.w = 0.0f;  // avoid 0*inf for deg-0 nodes
                }
                *(float4*)&h[(size_t)node * D_FEAT + fl * 4] = o;
            }
        }
    } else {
        // cnt == 0 (write zeros) or pathological overflow: filter directly from global.
        for (int nl = w; nl < 32; nl += 4) {
            int node = g * 32 + nl;
            if (node >= N_NODES) continue;
            float acc = 0.0f;
            int any = 0;
            for (unsigned int j = base; j < end; ++j) {
                unsigned int k = keysB[j];
                if ((int)((k >> 16) & 31) == nl) {
                    unsigned int s = k & 0xFFFFu;
                    acc = fmaf(x[(size_t)s * D_FEAT + lane], rs[s], acc);
                    any = 1;
                }
            }
            h[(size_t)node * D_FEAT + lane] = any ? acc * rs[node] : 0.0f;
        }
    }
}

// ---------- Fallback (tiny ws): atomic scatter ----------
__global__ void fb_degree_kernel(const int* __restrict__ src, unsigned int* __restrict__ deg,
                                 int n_edges) {
    int i = blockIdx.x * blockDim.x + threadIdx.x;
    int stride = gridDim.x * blockDim.x;
    for (; i < n_edges; i += stride) atomicAdd(&deg[src[i]], 1u);
}
__global__ void fb_scatter_kernel(const float* __restrict__ x, const int* __restrict__ src,
                                  const int* __restrict__ dst, const unsigned int* __restrict__ deg,
                                  float* __restrict__ h, int n_edges) {
    const int lane = threadIdx.x & 63;
    const int wave = (int)((blockIdx.x * blockDim.x + threadIdx.x) >> 6);
    const int nwaves = (int)((gridDim.x * blockDim.x) >> 6);
    for (int e = wave; e < n_edges; e += nwaves) {
        int s = __builtin_amdgcn_readfirstlane(src[e]);
        int d = __builtin_amdgcn_readfirstlane(dst[e]);
        float norm = rsqrtf((float)deg[s] * (float)deg[d]);
        atomicAdd(&h[d * D_FEAT + lane], x[s * D_FEAT + lane] * norm);
    }
}

// ---------- launch ----------
extern "C" void kernel_launch(void* const* d_in, const int* in_sizes, int n_in,
                              void* d_out, int out_size, void* d_ws, size_t ws_size,
                              hipStream_t stream) {
    const float* x   = (const float*)d_in[0];
    const int*   src = (const int*)d_in[1];
    const int*   dst = (const int*)d_in[2];
    float* h = (float*)d_out;

    // Workspace layout (~4.25 MB):
    //   keysB : N_EDGES u32 (3.2 MB) -- aliased with hp32 (64*12500 u32 = 3.2 MB);
    //           hp32 fully consumed by scanred_rs before bucket_scatter writes keysB.
    //   gh    : NSCAN u32 (0.82 MB)
    //   rs    : N_NODES f32 (200 KB)
    //   spart : 256 u32
    size_t off = 0;
    unsigned int*  keysB = (unsigned int*)((char*)d_ws + off);  off += (size_t)N_EDGES * 4;
    unsigned int*  hp32  = keysB;
    unsigned int*  gh    = (unsigned int*)((char*)d_ws + off);  off += (size_t)NSCAN * 4;
    float*         rs    = (float*)((char*)d_ws + off);         off += (size_t)N_NODES * 4;
    unsigned int*  spart = (unsigned int*)((char*)d_ws + off);  off += 256 * 4;

    if (ws_size >= off) {
        // No memsets: every workspace/output element is fully overwritten.
        hist_count_kernel<<<dim3(HCHUNKS + BSORT), dim3(256), 0, stream>>>(src, dst, hp32, gh);
        scanred_rs_kernel<<<dim3(SCAN_BLOCKS + RS_BLOCKS), dim3(SCAN_BLOCK), 0, stream>>>(
            gh, spart, (const unsigned char*)hp32, rs);
        scan_final_kernel<<<dim3(SCAN_BLOCKS), dim3(SCAN_BLOCK), 0, stream>>>(gh, spart);
        bucket_scatter_kernel<<<dim3(BSORT), dim3(1024), 0, stream>>>(src, dst, gh, keysB);
        bucket_aggregate_kernel<<<dim3(NAGG), dim3(256), 0, stream>>>(x, gh, keysB, rs, h);
    } else {
        // Fallback: atomic scatter (any ws >= 200 KB).
        unsigned int* deg = (unsigned int*)d_ws;
        hipMemsetAsync(deg, 0, N_NODES * sizeof(unsigned int), stream);
        hipMemsetAsync(d_out, 0, (size_t)out_size * sizeof(float), stream);
        fb_degree_kernel<<<dim3(1024), dim3(256), 0, stream>>>(src, deg, N_EDGES);
        fb_scatter_kernel<<<dim3(2048), dim3(256), 0, stream>>>(x, src, dst, deg, h, N_EDGES);
    }
}

// Round 12
// 61.151 us; speedup vs baseline: 1.2315x; 1.0224x over previous
//
#include <hip/hip_runtime.h>

#define N_NODES 50000
#define N_EDGES 800000
#define D_FEAT 64

// dst bucket sort: bucket = dst>>5 (32 nodes/bucket), 1563 used of 2048
#define NBINS 2048
#define BSORT 100                                    // sort blocks; N_EDGES/BSORT = 8000 exact
#define SORT_CHUNK (N_EDGES / BSORT)                 // 8000
#define NSCAN (NBINS * BSORT)                        // 204800 = 200*1024 exact
#define SCAN_BLOCK 1024
#define SCAN_BLOCKS (NSCAN / SCAN_BLOCK)             // 200
#define AGG_CAP 4096
#define NAGG ((N_NODES + 31) / 32)                   // 1563 buckets

// out-degree histogram: single pass, u8x4-packed LDS counters
#define HCHUNKS 64
#define HCHUNK (N_EDGES / HCHUNKS)                   // 12500 exact
#define HWORDS ((N_NODES + 3) / 4)                   // 12500 u32 = 50 KB LDS

#define RS_BLOCKS ((N_NODES + 255) / 256)            // 196

// ---------- Kernel 1 (fused): src out-degree histogram  ||  dst bucket counts ----------
// 512 threads (8 waves) per block to double LDS-atomic issue parallelism.
__global__ __launch_bounds__(512)
void hist_count_kernel(const int* __restrict__ src, const int* __restrict__ dst,
                       unsigned int* __restrict__ hp32, unsigned int* __restrict__ gh) {
    __shared__ unsigned int lh[HWORDS];  // 50 KB; count path uses first NBINS words
    const int b = blockIdx.x, t = threadIdx.x;
    if (b < HCHUNKS) {
        for (int i = t; i < HWORDS; i += 512) lh[i] = 0u;
        __syncthreads();
        const int4* s4 = (const int4*)(src + b * HCHUNK);
        for (int i = t; i < HCHUNK / 4; i += 512) {
            int4 v = s4[i];
            atomicAdd(&lh[v.x >> 2], 1u << ((v.x & 3) * 8));
            atomicAdd(&lh[v.y >> 2], 1u << ((v.y & 3) * 8));
            atomicAdd(&lh[v.z >> 2], 1u << ((v.z & 3) * 8));
            atomicAdd(&lh[v.w >> 2], 1u << ((v.w & 3) * 8));
        }
        __syncthreads();
        for (int w = t; w < HWORDS; w += 512)
            hp32[(size_t)b * HWORDS + w] = lh[w];
    } else {
        const int cb = b - HCHUNKS;
        for (int i = t; i < NBINS; i += 512) lh[i] = 0;
        __syncthreads();
        const int4* d4 = (const int4*)(dst + cb * SORT_CHUNK);
        for (int i = t; i < SORT_CHUNK / 4; i += 512) {
            int4 v = d4[i];
            atomicAdd(&lh[v.x >> 5], 1u);
            atomicAdd(&lh[v.y >> 5], 1u);
            atomicAdd(&lh[v.z >> 5], 1u);
            atomicAdd(&lh[v.w >> 5], 1u);
        }
        __syncthreads();
        for (int i = t; i < NBINS; i += 512) gh[(size_t)i * BSORT + cb] = lh[i];  // bin-major
    }
}

// ---------- Kernel 2 (fused): scan block-reduce  ||  degree merge + rs ----------
__global__ __launch_bounds__(SCAN_BLOCK)
void scanred_rs_kernel(const unsigned int* __restrict__ gh, unsigned int* __restrict__ partial,
                       const unsigned char* __restrict__ hp8, float* __restrict__ rs) {
    const int b = blockIdx.x;
    if (b < SCAN_BLOCKS) {
        __shared__ unsigned int wsum[SCAN_BLOCK / 64];
        int g = b * SCAN_BLOCK + threadIdx.x;
        unsigned int v = gh[g];
        for (int off = 32; off > 0; off >>= 1) v += __shfl_down(v, off, 64);
        if ((threadIdx.x & 63) == 0) wsum[threadIdx.x >> 6] = v;
        __syncthreads();
        if (threadIdx.x < SCAN_BLOCK / 64) {
            unsigned int s = wsum[threadIdx.x];
            for (int off = SCAN_BLOCK / 128; off > 0; off >>= 1) s += __shfl_down(s, off, 64);
            if (threadIdx.x == 0) partial[b] = s;
        }
    } else {
        if (threadIdx.x < 256) {
            int v = (b - SCAN_BLOCKS) * 256 + threadIdx.x;
            if (v < N_NODES) {
                unsigned int s = 0;
                #pragma unroll
                for (int c = 0; c < HCHUNKS; ++c) s += hp8[(size_t)c * (HWORDS * 4) + v];
                rs[v] = rsqrtf((float)s);
            }
        }
    }
}

// ---------- Kernel 3: scan finalize (in-LDS re-scan of the 200 partials) ----------
__global__ __launch_bounds__(SCAN_BLOCK)
void scan_final_kernel(unsigned int* __restrict__ data, const unsigned int* __restrict__ partial) {
    __shared__ unsigned int arr[SCAN_BLOCK];
    __shared__ unsigned int pbase[256];
    const int t = threadIdx.x;
    const int g = blockIdx.x * SCAN_BLOCK + t;
    if (t < 256) pbase[t] = (t < SCAN_BLOCKS) ? partial[t] : 0u;
    __syncthreads();
    for (int off = 1; off < 256; off <<= 1) {
        unsigned int u = (t < 256 && t >= off) ? pbase[t - off] : 0u;
        __syncthreads();
        if (t < 256 && t >= off) pbase[t] += u;
        __syncthreads();
    }
    const unsigned int base = (blockIdx.x == 0) ? 0u : pbase[blockIdx.x - 1];
    unsigned int v = data[g];
    arr[t] = v;
    __syncthreads();
    for (int off = 1; off < SCAN_BLOCK; off <<= 1) {
        unsigned int u = (t >= off) ? arr[t - off] : 0u;
        __syncthreads();
        arr[t] += u;
        __syncthreads();
    }
    data[g] = base + arr[t] - v;  // exclusive, in-place
}

// ---------- Kernel 4: scatter keys via LDS cursors; 1024 threads for TLP ----------
__global__ __launch_bounds__(1024)
void bucket_scatter_kernel(const int* __restrict__ src, const int* __restrict__ dst,
                           const unsigned int* __restrict__ gh, unsigned int* __restrict__ keysB) {
    __shared__ unsigned int cur[NBINS];  // 8 KB
    const int b = blockIdx.x, t = threadIdx.x;
    for (int i = t; i < NBINS; i += 1024) cur[i] = gh[(size_t)i * BSORT + b];
    __syncthreads();
    const int4* s4 = (const int4*)(src + b * SORT_CHUNK);
    const int4* d4 = (const int4*)(dst + b * SORT_CHUNK);
    for (int i = t; i < SORT_CHUNK / 4; i += 1024) {
        int4 s = s4[i];
        int4 d = d4[i];
        unsigned int p0 = atomicAdd(&cur[d.x >> 5], 1u);
        keysB[p0] = ((unsigned int)d.x << 16) | (unsigned int)s.x;
        unsigned int p1 = atomicAdd(&cur[d.y >> 5], 1u);
        keysB[p1] = ((unsigned int)d.y << 16) | (unsigned int)s.y;
        unsigned int p2 = atomicAdd(&cur[d.z >> 5], 1u);
        keysB[p2] = ((unsigned int)d.z << 16) | (unsigned int)s.z;
        unsigned int p3 = atomicAdd(&cur[d.w >> 5], 1u);
        keysB[p3] = ((unsigned int)d.w << 16) | (unsigned int)s.w;
    }
}

// ---------- Kernel 5: block per bucket, 512 threads (8 waves x 4 nodes) ----------
__global__ __launch_bounds__(512)
void bucket_aggregate_kernel(const float* __restrict__ x, const unsigned int* __restrict__ gh,
                             const unsigned int* __restrict__ keysB, const float* __restrict__ rs,
                             float* __restrict__ h) {
    __shared__ unsigned int ebuf[AGG_CAP];  // 16 KB
    __shared__ unsigned int ecnt[32];
    __shared__ unsigned int eoff[33];
    const int g = blockIdx.x;
    const int t = threadIdx.x;
    const int lane = t & 63;
    const int w = t >> 6;                  // 0..7
    const unsigned int base = gh[(size_t)g * BSORT];
    const unsigned int end  = gh[(size_t)(g + 1) * BSORT];
    const int cnt = (int)(end - base);

    if (cnt > 0 && cnt <= AGG_CAP) {  // block-uniform branch
        if (t < 32) ecnt[t] = 0;
        __syncthreads();
        for (int i = t; i < cnt; i += 512) atomicAdd(&ecnt[(keysB[base + i] >> 16) & 31], 1u);
        __syncthreads();
        if (t == 0) {
            unsigned int r = 0;
            for (int k2 = 0; k2 < 32; ++k2) { eoff[k2] = r; r += ecnt[k2]; }
            eoff[32] = r;
        }
        __syncthreads();
        if (t < 32) ecnt[t] = eoff[t];  // reuse as cursors
        __syncthreads();
        for (int i = t; i < cnt; i += 512) {
            unsigned int k = keysB[base + i];
            ebuf[atomicAdd(&ecnt[(k >> 16) & 31], 1u)] = k;
        }
        __syncthreads();

        const int grp = lane >> 4;   // edge sub-group 0..3
        const int fl  = lane & 15;   // float4 slot within the 64-feature row
        for (int nl = w; nl < 32; nl += 8) {
            int node = g * 32 + nl;
            if (node >= N_NODES) continue;
            const int jb = (int)eoff[nl];
            const int m  = (int)eoff[nl + 1] - jb;
            float ax = 0.0f, ay = 0.0f, az = 0.0f, aw = 0.0f;
            int jj = 0;
            // main: 8 edges per iteration (2 x dwordx4 in flight per wave)
            for (; jj + 8 <= m; jj += 8) {
                unsigned int s0 = ebuf[jb + jj + grp] & 0xFFFFu;
                unsigned int s1 = ebuf[jb + jj + 4 + grp] & 0xFFFFu;
                const float4 v0 = *(const float4*)&x[(size_t)s0 * D_FEAT + fl * 4];
                const float4 v1 = *(const float4*)&x[(size_t)s1 * D_FEAT + fl * 4];
                float w0 = rs[s0], w1 = rs[s1];
                ax = fmaf(v0.x, w0, ax); ay = fmaf(v0.y, w0, ay);
                az = fmaf(v0.z, w0, az); aw = fmaf(v0.w, w0, aw);
                ax = fmaf(v1.x, w1, ax); ay = fmaf(v1.y, w1, ay);
                az = fmaf(v1.z, w1, az); aw = fmaf(v1.w, w1, aw);
            }
            // tail: up to 7 edges, two masked groups-of-4
            if (jj < m) {
                int idx = jj + grp;
                unsigned int s = ebuf[jb + min(idx, m - 1)] & 0xFFFFu;
                float wgt = (idx < m) ? rs[s] : 0.0f;
                const float4 v = *(const float4*)&x[(size_t)s * D_FEAT + fl * 4];
                ax = fmaf(v.x, wgt, ax); ay = fmaf(v.y, wgt, ay);
                az = fmaf(v.z, wgt, az); aw = fmaf(v.w, wgt, aw);
                jj += 4;
                if (jj < m) {
                    idx = jj + grp;
                    unsigned int s2 = ebuf[jb + min(idx, m - 1)] & 0xFFFFu;
                    float wgt2 = (idx < m) ? rs[s2] : 0.0f;
                    const float4 v2 = *(const float4*)&x[(size_t)s2 * D_FEAT + fl * 4];
                    ax = fmaf(v2.x, wgt2, ax); ay = fmaf(v2.y, wgt2, ay);
                    az = fmaf(v2.z, wgt2, az); aw = fmaf(v2.w, wgt2, aw);
                }
            }
            // combine the 4 edge sub-groups: lanes l, l^16, l^32
            ax += __shfl_xor(ax, 16, 64); ay += __shfl_xor(ay, 16, 64);
            az += __shfl_xor(az, 16, 64); aw += __shfl_xor(aw, 16, 64);
            ax += __shfl_xor(ax, 32, 64); ay += __shfl_xor(ay, 32, 64);
            az += __shfl_xor(az, 32, 64); aw += __shfl_xor(aw, 32, 64);
            if (lane < 16) {
                float4 o;
                if (m > 0) {
                    const float rsn = rs[node];
                    o.x = ax * rsn; o.y = ay * rsn; o.z = az * rsn; o.w = aw * rsn;
                } else {
                    o.x = o.y = o.z = o.w = 0.0f;  // avoid 0*inf for deg-0 nodes
                }
                *(float4*)&h[(size_t)node * D_FEAT + fl * 4] = o;
            }
        }
    } else {
        // cnt == 0 (write zeros) or pathological overflow: filter directly from global.
        for (int nl = w; nl < 32; nl += 8) {
            int node = g * 32 + nl;
            if (node >= N_NODES) continue;
            float acc = 0.0f;
            int any = 0;
            for (unsigned int j = base; j < end; ++j) {
                unsigned int k = keysB[j];
                if ((int)((k >> 16) & 31) == nl) {
                    unsigned int s = k & 0xFFFFu;
                    acc = fmaf(x[(size_t)s * D_FEAT + lane], rs[s], acc);
                    any = 1;
                }
            }
            h[(size_t)node * D_FEAT + lane] = any ? acc * rs[node] : 0.0f;
        }
    }
}

// ---------- Fallback (tiny ws): atomic scatter ----------
__global__ void fb_degree_kernel(const int* __restrict__ src, unsigned int* __restrict__ deg,
                                 int n_edges) {
    int i = blockIdx.x * blockDim.x + threadIdx.x;
    int stride = gridDim.x * blockDim.x;
    for (; i < n_edges; i += stride) atomicAdd(&deg[src[i]], 1u);
}
__global__ void fb_scatter_kernel(const float* __restrict__ x, const int* __restrict__ src,
                                  const int* __restrict__ dst, const unsigned int* __restrict__ deg,
                                  float* __restrict__ h, int n_edges) {
    const int lane = threadIdx.x & 63;
    const int wave = (int)((blockIdx.x * blockDim.x + threadIdx.x) >> 6);
    const int nwaves = (int)((gridDim.x * blockDim.x) >> 6);
    for (int e = wave; e < n_edges; e += nwaves) {
        int s = __builtin_amdgcn_readfirstlane(src[e]);
        int d = __builtin_amdgcn_readfirstlane(dst[e]);
        float norm = rsqrtf((float)deg[s] * (float)deg[d]);
        atomicAdd(&h[d * D_FEAT + lane], x[s * D_FEAT + lane] * norm);
    }
}

// ---------- launch ----------
extern "C" void kernel_launch(void* const* d_in, const int* in_sizes, int n_in,
                              void* d_out, int out_size, void* d_ws, size_t ws_size,
                              hipStream_t stream) {
    const float* x   = (const float*)d_in[0];
    const int*   src = (const int*)d_in[1];
    const int*   dst = (const int*)d_in[2];
    float* h = (float*)d_out;

    // Workspace layout (~4.25 MB):
    //   keysB : N_EDGES u32 (3.2 MB) -- aliased with hp32 (64*12500 u32 = 3.2 MB);
    //           hp32 fully consumed by scanred_rs before bucket_scatter writes keysB.
    //   gh    : NSCAN u32 (0.82 MB)
    //   rs    : N_NODES f32 (200 KB)
    //   spart : 256 u32
    size_t off = 0;
    unsigned int*  keysB = (unsigned int*)((char*)d_ws + off);  off += (size_t)N_EDGES * 4;
    unsigned int*  hp32  = keysB;
    unsigned int*  gh    = (unsigned int*)((char*)d_ws + off);  off += (size_t)NSCAN * 4;
    float*         rs    = (float*)((char*)d_ws + off);         off += (size_t)N_NODES * 4;
    unsigned int*  spart = (unsigned int*)((char*)d_ws + off);  off += 256 * 4;

    if (ws_size >= off) {
        // No memsets: every workspace/output element is fully overwritten.
        hist_count_kernel<<<dim3(HCHUNKS + BSORT), dim3(512), 0, stream>>>(src, dst, hp32, gh);
        scanred_rs_kernel<<<dim3(SCAN_BLOCKS + RS_BLOCKS), dim3(SCAN_BLOCK), 0, stream>>>(
            gh, spart, (const unsigned char*)hp32, rs);
        scan_final_kernel<<<dim3(SCAN_BLOCKS), dim3(SCAN_BLOCK), 0, stream>>>(gh, spart);
        bucket_scatter_kernel<<<dim3(BSORT), dim3(1024), 0, stream>>>(src, dst, gh, keysB);
        bucket_aggregate_kernel<<<dim3(NAGG), dim3(512), 0, stream>>>(x, gh, keysB, rs, h);
    } else {
        // Fallback: atomic scatter (any ws >= 200 KB).
        unsigned int* deg = (unsigned int*)d_ws;
        hipMemsetAsync(deg, 0, N_NODES * sizeof(unsigned int), stream);
        hipMemsetAsync(d_out, 0, (size_t)out_size * sizeof(float), stream);
        fb_degree_kernel<<<dim3(1024), dim3(256), 0, stream>>>(src, deg, N_EDGES);
        fb_scatter_kernel<<<dim3(2048), dim3(256), 0, stream>>>(x, src, dst, deg, h, N_EDGES);
    }
}

// Round 13
// 57.784 us; speedup vs baseline: 1.3032x; 1.0583x over previous
//
#include <hip/hip_runtime.h>

#define N_NODES 50000
#define N_EDGES 800000
#define D_FEAT 64

// dst bucket sort: bucket = dst>>6 (64 nodes/bucket), 782 used of 1024
#define NBINS 1024
#define BSORT 100                                    // sort blocks; N_EDGES/BSORT = 8000 exact
#define SORT_CHUNK (N_EDGES / BSORT)                 // 8000
#define NSCAN (NBINS * BSORT)                        // 102400 = 100*1024 exact
#define SCAN_BLOCK 1024
#define SCAN_BLOCKS (NSCAN / SCAN_BLOCK)             // 100
#define AGG_CAP 3072
#define NAGG ((N_NODES + 63) / 64)                   // 782 buckets

// out-degree histogram: single pass, u8x4-packed LDS counters
#define HCHUNKS 64
#define HCHUNK (N_EDGES / HCHUNKS)                   // 12500 exact
#define HWORDS ((N_NODES + 3) / 4)                   // 12500 u32 = 50 KB LDS

#define RS_BLOCKS ((N_NODES + 255) / 256)            // 196

// ---------- Kernel 1 (fused): src out-degree histogram  ||  dst bucket counts ----------
__global__ __launch_bounds__(512)
void hist_count_kernel(const int* __restrict__ src, const int* __restrict__ dst,
                       unsigned int* __restrict__ hp32, unsigned int* __restrict__ gh) {
    __shared__ unsigned int lh[HWORDS];  // 50 KB; count path uses first NBINS words
    const int b = blockIdx.x, t = threadIdx.x;
    if (b < HCHUNKS) {
        for (int i = t; i < HWORDS; i += 512) lh[i] = 0u;
        __syncthreads();
        const int4* s4 = (const int4*)(src + b * HCHUNK);
        for (int i = t; i < HCHUNK / 4; i += 512) {
            int4 v = s4[i];
            atomicAdd(&lh[v.x >> 2], 1u << ((v.x & 3) * 8));
            atomicAdd(&lh[v.y >> 2], 1u << ((v.y & 3) * 8));
            atomicAdd(&lh[v.z >> 2], 1u << ((v.z & 3) * 8));
            atomicAdd(&lh[v.w >> 2], 1u << ((v.w & 3) * 8));
        }
        __syncthreads();
        for (int w = t; w < HWORDS; w += 512)
            hp32[(size_t)b * HWORDS + w] = lh[w];
    } else {
        const int cb = b - HCHUNKS;
        for (int i = t; i < NBINS; i += 512) lh[i] = 0;
        __syncthreads();
        const int4* d4 = (const int4*)(dst + cb * SORT_CHUNK);
        for (int i = t; i < SORT_CHUNK / 4; i += 512) {
            int4 v = d4[i];
            atomicAdd(&lh[v.x >> 6], 1u);
            atomicAdd(&lh[v.y >> 6], 1u);
            atomicAdd(&lh[v.z >> 6], 1u);
            atomicAdd(&lh[v.w >> 6], 1u);
        }
        __syncthreads();
        for (int i = t; i < NBINS; i += 512) gh[(size_t)i * BSORT + cb] = lh[i];  // bin-major
    }
}

// ---------- Kernel 2 (fused): scan block-reduce  ||  degree merge + rs ----------
__global__ __launch_bounds__(SCAN_BLOCK)
void scanred_rs_kernel(const unsigned int* __restrict__ gh, unsigned int* __restrict__ partial,
                       const unsigned char* __restrict__ hp8, float* __restrict__ rs) {
    const int b = blockIdx.x;
    if (b < SCAN_BLOCKS) {
        __shared__ unsigned int wsum[SCAN_BLOCK / 64];
        int g = b * SCAN_BLOCK + threadIdx.x;
        unsigned int v = gh[g];
        for (int off = 32; off > 0; off >>= 1) v += __shfl_down(v, off, 64);
        if ((threadIdx.x & 63) == 0) wsum[threadIdx.x >> 6] = v;
        __syncthreads();
        if (threadIdx.x < SCAN_BLOCK / 64) {
            unsigned int s = wsum[threadIdx.x];
            for (int off = SCAN_BLOCK / 128; off > 0; off >>= 1) s += __shfl_down(s, off, 64);
            if (threadIdx.x == 0) partial[b] = s;
        }
    } else {
        if (threadIdx.x < 256) {
            int v = (b - SCAN_BLOCKS) * 256 + threadIdx.x;
            if (v < N_NODES) {
                unsigned int s = 0;
                #pragma unroll
                for (int c = 0; c < HCHUNKS; ++c) s += hp8[(size_t)c * (HWORDS * 4) + v];
                rs[v] = rsqrtf((float)s);
            }
        }
    }
}

// ---------- Kernel 3: scan finalize, barrier-light (shfl scans, 2 barriers) ----------
__global__ __launch_bounds__(SCAN_BLOCK)
void scan_final_kernel(unsigned int* __restrict__ data, const unsigned int* __restrict__ partial) {
    __shared__ unsigned int wsum[SCAN_BLOCK / 64];  // 16 wave sums
    __shared__ unsigned int red2[2];
    const int t = threadIdx.x;
    const int lane = t & 63;
    const int wid = t >> 6;
    const int g = blockIdx.x * SCAN_BLOCK + t;

    // block base = sum(partial[0..bid-1]); threads t<bid (bid<=99) hold values, 2-wave reduce
    unsigned int p = (t < blockIdx.x) ? partial[t] : 0u;
    if (t < 128) {
        for (int off = 32; off > 0; off >>= 1) p += __shfl_down(p, off, 64);
        if (lane == 0) red2[wid] = p;
    }

    // wave-level inclusive scan of this block's 1024 elements
    unsigned int v = data[g];
    unsigned int sc = v;
    for (int off = 1; off < 64; off <<= 1) {
        unsigned int u = __shfl_up(sc, off, 64);
        if (lane >= off) sc += u;
    }
    if (lane == 63) wsum[wid] = sc;
    __syncthreads();
    if (t < SCAN_BLOCK / 64) {  // wave 0 scans the 16 wave sums
        unsigned int q = wsum[t];
        for (int off = 1; off < SCAN_BLOCK / 64; off <<= 1) {
            unsigned int u = __shfl_up(q, off, 64);
            if (t >= off) q += u;
        }
        wsum[t] = q;  // inclusive
    }
    __syncthreads();
    const unsigned int base = red2[0] + red2[1];
    const unsigned int wbase = (wid == 0) ? 0u : wsum[wid - 1];
    data[g] = base + wbase + sc - v;  // exclusive, in-place
}

// ---------- Kernel 4: scatter keys via LDS cursors; 1024 threads for TLP ----------
__global__ __launch_bounds__(1024)
void bucket_scatter_kernel(const int* __restrict__ src, const int* __restrict__ dst,
                           const unsigned int* __restrict__ gh, unsigned int* __restrict__ keysB) {
    __shared__ unsigned int cur[NBINS];  // 4 KB
    const int b = blockIdx.x, t = threadIdx.x;
    if (t < NBINS) cur[t] = gh[(size_t)t * BSORT + b];
    __syncthreads();
    const int4* s4 = (const int4*)(src + b * SORT_CHUNK);
    const int4* d4 = (const int4*)(dst + b * SORT_CHUNK);
    for (int i = t; i < SORT_CHUNK / 4; i += 1024) {
        int4 s = s4[i];
        int4 d = d4[i];
        unsigned int p0 = atomicAdd(&cur[d.x >> 6], 1u);
        keysB[p0] = ((unsigned int)d.x << 16) | (unsigned int)s.x;
        unsigned int p1 = atomicAdd(&cur[d.y >> 6], 1u);
        keysB[p1] = ((unsigned int)d.y << 16) | (unsigned int)s.y;
        unsigned int p2 = atomicAdd(&cur[d.z >> 6], 1u);
        keysB[p2] = ((unsigned int)d.z << 16) | (unsigned int)s.z;
        unsigned int p3 = atomicAdd(&cur[d.w >> 6], 1u);
        keysB[p3] = ((unsigned int)d.w << 16) | (unsigned int)s.w;
    }
}

// ---------- Kernel 5: block per bucket (64 nodes), 512 threads (8 waves x 8 nodes) ----------
__global__ __launch_bounds__(512)
void bucket_aggregate_kernel(const float* __restrict__ x, const unsigned int* __restrict__ gh,
                             const unsigned int* __restrict__ keysB, const float* __restrict__ rs,
                             float* __restrict__ h) {
    __shared__ unsigned int ebuf[AGG_CAP];  // 12 KB
    __shared__ unsigned int ecnt[64];
    __shared__ unsigned int eoff[65];
    const int g = blockIdx.x;
    const int t = threadIdx.x;
    const int lane = t & 63;
    const int w = t >> 6;                  // 0..7
    const unsigned int base = gh[(size_t)g * BSORT];
    const unsigned int end  = gh[(size_t)(g + 1) * BSORT];
    const int cnt = (int)(end - base);

    if (cnt > 0 && cnt <= AGG_CAP) {  // block-uniform branch
        if (t < 64) ecnt[t] = 0;
        __syncthreads();
        for (int i = t; i < cnt; i += 512) atomicAdd(&ecnt[(keysB[base + i] >> 16) & 63], 1u);
        __syncthreads();
        if (t < 64) {  // wave-0 shfl scan of 64 bin counts
            unsigned int c = ecnt[t];
            unsigned int q = c;
            for (int off = 1; off < 64; off <<= 1) {
                unsigned int u = __shfl_up(q, off, 64);
                if (lane >= off) q += u;
            }
            eoff[t] = q - c;          // exclusive
            if (t == 63) eoff[64] = q;
        }
        __syncthreads();
        if (t < 64) ecnt[t] = eoff[t];  // reuse as cursors
        __syncthreads();
        for (int i = t; i < cnt; i += 512) {
            unsigned int k = keysB[base + i];
            ebuf[atomicAdd(&ecnt[(k >> 16) & 63], 1u)] = k;
        }
        __syncthreads();

        const int grp = lane >> 4;   // edge sub-group 0..3
        const int fl  = lane & 15;   // float4 slot within the 64-feature row
        for (int nl = w; nl < 64; nl += 8) {
            int node = g * 64 + nl;
            if (node >= N_NODES) continue;
            const int jb = (int)eoff[nl];
            const int m  = (int)eoff[nl + 1] - jb;
            float ax = 0.0f, ay = 0.0f, az = 0.0f, aw = 0.0f;
            int jj = 0;
            // main: 8 edges per iteration (2 x dwordx4 in flight per wave)
            for (; jj + 8 <= m; jj += 8) {
                unsigned int s0 = ebuf[jb + jj + grp] & 0xFFFFu;
                unsigned int s1 = ebuf[jb + jj + 4 + grp] & 0xFFFFu;
                const float4 v0 = *(const float4*)&x[(size_t)s0 * D_FEAT + fl * 4];
                const float4 v1 = *(const float4*)&x[(size_t)s1 * D_FEAT + fl * 4];
                float w0 = rs[s0], w1 = rs[s1];
                ax = fmaf(v0.x, w0, ax); ay = fmaf(v0.y, w0, ay);
                az = fmaf(v0.z, w0, az); aw = fmaf(v0.w, w0, aw);
                ax = fmaf(v1.x, w1, ax); ay = fmaf(v1.y, w1, ay);
                az = fmaf(v1.z, w1, az); aw = fmaf(v1.w, w1, aw);
            }
            // tail: up to 7 edges, two masked groups-of-4
            if (jj < m) {
                int idx = jj + grp;
                unsigned int s = ebuf[jb + min(idx, m - 1)] & 0xFFFFu;
                float wgt = (idx < m) ? rs[s] : 0.0f;
                const float4 v = *(const float4*)&x[(size_t)s * D_FEAT + fl * 4];
                ax = fmaf(v.x, wgt, ax); ay = fmaf(v.y, wgt, ay);
                az = fmaf(v.z, wgt, az); aw = fmaf(v.w, wgt, aw);
                jj += 4;
                if (jj < m) {
                    idx = jj + grp;
                    unsigned int s2 = ebuf[jb + min(idx, m - 1)] & 0xFFFFu;
                    float wgt2 = (idx < m) ? rs[s2] : 0.0f;
                    const float4 v2 = *(const float4*)&x[(size_t)s2 * D_FEAT + fl * 4];
                    ax = fmaf(v2.x, wgt2, ax); ay = fmaf(v2.y, wgt2, ay);
                    az = fmaf(v2.z, wgt2, az); aw = fmaf(v2.w, wgt2, aw);
                }
            }
            // combine the 4 edge sub-groups: lanes l, l^16, l^32
            ax += __shfl_xor(ax, 16, 64); ay += __shfl_xor(ay, 16, 64);
            az += __shfl_xor(az, 16, 64); aw += __shfl_xor(aw, 16, 64);
            ax += __shfl_xor(ax, 32, 64); ay += __shfl_xor(ay, 32, 64);
            az += __shfl_xor(az, 32, 64); aw += __shfl_xor(aw, 32, 64);
            if (lane < 16) {
                float4 o;
                if (m > 0) {
                    const float rsn = rs[node];
                    o.x = ax * rsn; o.y = ay * rsn; o.z = az * rsn; o.w = aw * rsn;
                } else {
                    o.x = o.y = o.z = o.w = 0.0f;  // avoid 0*inf for deg-0 nodes
                }
                *(float4*)&h[(size_t)node * D_FEAT + fl * 4] = o;
            }
        }
    } else {
        // cnt == 0 (write zeros) or pathological overflow: filter directly from global.
        for (int nl = w; nl < 64; nl += 8) {
            int node = g * 64 + nl;
            if (node >= N_NODES) continue;
            float acc = 0.0f;
            int any = 0;
            for (unsigned int j = base; j < end; ++j) {
                unsigned int k = keysB[j];
                if ((int)((k >> 16) & 63) == nl) {
                    unsigned int s = k & 0xFFFFu;
                    acc = fmaf(x[(size_t)s * D_FEAT + lane], rs[s], acc);
                    any = 1;
                }
            }
            h[(size_t)node * D_FEAT + lane] = any ? acc * rs[node] : 0.0f;
        }
    }
}

// ---------- Fallback (tiny ws): atomic scatter ----------
__global__ void fb_degree_kernel(const int* __restrict__ src, unsigned int* __restrict__ deg,
                                 int n_edges) {
    int i = blockIdx.x * blockDim.x + threadIdx.x;
    int stride = gridDim.x * blockDim.x;
    for (; i < n_edges; i += stride) atomicAdd(&deg[src[i]], 1u);
}
__global__ void fb_scatter_kernel(const float* __restrict__ x, const int* __restrict__ src,
                                  const int* __restrict__ dst, const unsigned int* __restrict__ deg,
                                  float* __restrict__ h, int n_edges) {
    const int lane = threadIdx.x & 63;
    const int wave = (int)((blockIdx.x * blockDim.x + threadIdx.x) >> 6);
    const int nwaves = (int)((gridDim.x * blockDim.x) >> 6);
    for (int e = wave; e < n_edges; e += nwaves) {
        int s = __builtin_amdgcn_readfirstlane(src[e]);
        int d = __builtin_amdgcn_readfirstlane(dst[e]);
        float norm = rsqrtf((float)deg[s] * (float)deg[d]);
        atomicAdd(&h[d * D_FEAT + lane], x[s * D_FEAT + lane] * norm);
    }
}

// ---------- launch ----------
extern "C" void kernel_launch(void* const* d_in, const int* in_sizes, int n_in,
                              void* d_out, int out_size, void* d_ws, size_t ws_size,
                              hipStream_t stream) {
    const float* x   = (const float*)d_in[0];
    const int*   src = (const int*)d_in[1];
    const int*   dst = (const int*)d_in[2];
    float* h = (float*)d_out;

    // Workspace layout (~3.85 MB):
    //   keysB : N_EDGES u32 (3.2 MB) -- aliased with hp32 (64*12500 u32 = 3.2 MB);
    //           hp32 fully consumed by scanred_rs before bucket_scatter writes keysB.
    //   gh    : NSCAN u32 (0.41 MB)
    //   rs    : N_NODES f32 (200 KB)
    //   spart : 128 u32
    size_t off = 0;
    unsigned int*  keysB = (unsigned int*)((char*)d_ws + off);  off += (size_t)N_EDGES * 4;
    unsigned int*  hp32  = keysB;
    unsigned int*  gh    = (unsigned int*)((char*)d_ws + off);  off += (size_t)NSCAN * 4;
    float*         rs    = (float*)((char*)d_ws + off);         off += (size_t)N_NODES * 4;
    unsigned int*  spart = (unsigned int*)((char*)d_ws + off);  off += 128 * 4;

    if (ws_size >= off) {
        // No memsets: every workspace/output element is fully overwritten.
        hist_count_kernel<<<dim3(HCHUNKS + BSORT), dim3(512), 0, stream>>>(src, dst, hp32, gh);
        scanred_rs_kernel<<<dim3(SCAN_BLOCKS + RS_BLOCKS), dim3(SCAN_BLOCK), 0, stream>>>(
            gh, spart, (const unsigned char*)hp32, rs);
        scan_final_kernel<<<dim3(SCAN_BLOCKS), dim3(SCAN_BLOCK), 0, stream>>>(gh, spart);
        bucket_scatter_kernel<<<dim3(BSORT), dim3(1024), 0, stream>>>(src, dst, gh, keysB);
        bucket_aggregate_kernel<<<dim3(NAGG), dim3(512), 0, stream>>>(x, gh, keysB, rs, h);
    } else {
        // Fallback: atomic scatter (any ws >= 200 KB).
        unsigned int* deg = (unsigned int*)d_ws;
        hipMemsetAsync(deg, 0, N_NODES * sizeof(unsigned int), stream);
        hipMemsetAsync(d_out, 0, (size_t)out_size * sizeof(float), stream);
        fb_degree_kernel<<<dim3(1024), dim3(256), 0, stream>>>(src, deg, N_EDGES);
        fb_scatter_kernel<<<dim3(2048), dim3(256), 0, stream>>>(x, src, dst, deg, h, N_EDGES);
    }
}

// Round 14
// 56.143 us; speedup vs baseline: 1.3413x; 1.0292x over previous
//
#include <hip/hip_runtime.h>

#define N_NODES 50000
#define N_EDGES 800000
#define D_FEAT 64

// dst bucket sort: bucket = dst>>6 (64 nodes/bucket), 782 used of 1024
#define NBINS 1024
#define BSORT 200                                    // sort blocks; N_EDGES/BSORT = 4000 exact
#define SORT_CHUNK (N_EDGES / BSORT)                 // 4000
#define NSCAN (NBINS * BSORT)                        // 204800
#define AGG_CAP 3072
#define NAGG ((N_NODES + 63) / 64)                   // 782 buckets

// out-degree histogram: single pass, u8x4-packed LDS counters
#define HCHUNKS 64
#define HCHUNK (N_EDGES / HCHUNKS)                   // 12500 exact
#define HWORDS ((N_NODES + 3) / 4)                   // 12500 u32 = 50 KB LDS

#define BINSCAN_BLOCKS (NBINS / 16)                  // 64 blocks x 16 waves = 1024 bins
#define RS_BLOCKS ((N_NODES + 1023) / 1024)          // 49

// ---------- Kernel 1 (fused): src out-degree histogram  ||  dst bucket counts ----------
__global__ __launch_bounds__(512)
void hist_count_kernel(const int* __restrict__ src, const int* __restrict__ dst,
                       unsigned int* __restrict__ hp32, unsigned int* __restrict__ gh) {
    __shared__ unsigned int lh[HWORDS];  // 50 KB; count path uses first NBINS words
    const int b = blockIdx.x, t = threadIdx.x;
    if (b < HCHUNKS) {
        for (int i = t; i < HWORDS; i += 512) lh[i] = 0u;
        __syncthreads();
        const int4* s4 = (const int4*)(src + b * HCHUNK);
        for (int i = t; i < HCHUNK / 4; i += 512) {
            int4 v = s4[i];
            atomicAdd(&lh[v.x >> 2], 1u << ((v.x & 3) * 8));
            atomicAdd(&lh[v.y >> 2], 1u << ((v.y & 3) * 8));
            atomicAdd(&lh[v.z >> 2], 1u << ((v.z & 3) * 8));
            atomicAdd(&lh[v.w >> 2], 1u << ((v.w & 3) * 8));
        }
        __syncthreads();
        for (int w = t; w < HWORDS; w += 512)
            hp32[(size_t)b * HWORDS + w] = lh[w];
    } else {
        const int cb = b - HCHUNKS;
        for (int i = t; i < NBINS; i += 512) lh[i] = 0;
        __syncthreads();
        const int4* d4 = (const int4*)(dst + cb * SORT_CHUNK);
        for (int i = t; i < SORT_CHUNK / 4; i += 512) {
            int4 v = d4[i];
            atomicAdd(&lh[v.x >> 6], 1u);
            atomicAdd(&lh[v.y >> 6], 1u);
            atomicAdd(&lh[v.z >> 6], 1u);
            atomicAdd(&lh[v.w >> 6], 1u);
        }
        __syncthreads();
        for (int i = t; i < NBINS; i += 512) gh[(size_t)i * BSORT + cb] = lh[i];  // bin-major
    }
}

// ---------- Kernel 2 (fused): per-bin-row exclusive scan (wave per bin)  ||  rs merge ----------
// Blocks [0, BINSCAN_BLOCKS): wave w scans bin i = b*16+w's contiguous 200-entry row
// in-register (4 vals/lane via int4), writes back within-row exclusive prefixes + binsum[i].
// Blocks [BINSCAN_BLOCKS, +RS_BLOCKS): rs[v] = rsqrt(sum of 64 u8 degree partials).
__global__ __launch_bounds__(1024)
void binscan_rs_kernel(unsigned int* __restrict__ gh, unsigned int* __restrict__ binsum,
                       const unsigned char* __restrict__ hp8, float* __restrict__ rs) {
    const int b = blockIdx.x, t = threadIdx.x;
    if (b < BINSCAN_BLOCKS) {
        const int lane = t & 63;
        const int i = b * 16 + (t >> 6);  // bin
        uint4 c = make_uint4(0u, 0u, 0u, 0u);
        unsigned int* row = gh + (size_t)i * BSORT;
        if (lane * 4 < BSORT) c = *(const uint4*)(row + lane * 4);
        unsigned int tot = c.x + c.y + c.z + c.w;
        unsigned int q = tot;
        for (int off = 1; off < 64; off <<= 1) {
            unsigned int u = __shfl_up(q, off, 64);
            if (lane >= off) q += u;
        }
        const unsigned int ebase = q - tot;  // exclusive across lanes
        if (lane * 4 < BSORT) {
            uint4 o;
            o.x = ebase;
            o.y = ebase + c.x;
            o.z = ebase + c.x + c.y;
            o.w = ebase + c.x + c.y + c.z;
            *(uint4*)(row + lane * 4) = o;
        }
        unsigned int total = __shfl(q, 63, 64);
        if (lane == 0) binsum[i] = total;
    } else {
        int v = (b - BINSCAN_BLOCKS) * 1024 + t;
        if (v < N_NODES) {
            unsigned int s = 0;
            #pragma unroll
            for (int c2 = 0; c2 < HCHUNKS; ++c2) s += hp8[(size_t)c2 * (HWORDS * 4) + v];
            rs[v] = rsqrtf((float)s);
        }
    }
}

// ---------- Kernel 3: scatter keys via LDS cursors (block-scans binsum for bases) ----------
__global__ __launch_bounds__(1024)
void bucket_scatter_kernel(const int* __restrict__ src, const int* __restrict__ dst,
                           const unsigned int* __restrict__ gh,
                           const unsigned int* __restrict__ binsum,
                           unsigned int* __restrict__ binoffG,
                           unsigned int* __restrict__ keysB) {
    __shared__ unsigned int cur[NBINS];  // 4 KB
    __shared__ unsigned int wsums[16];
    const int b = blockIdx.x, t = threadIdx.x;
    const int lane = t & 63, wid = t >> 6;

    // block-wide exclusive scan of the 1024 binsums -> binoff
    unsigned int bs = binsum[t];
    unsigned int q = bs;
    for (int off = 1; off < 64; off <<= 1) {
        unsigned int u = __shfl_up(q, off, 64);
        if (lane >= off) q += u;
    }
    if (lane == 63) wsums[wid] = q;
    __syncthreads();
    if (t < 16) {
        unsigned int r = wsums[t];
        for (int off = 1; off < 16; off <<= 1) {
            unsigned int u = __shfl_up(r, off, 64);
            if (t >= off) r += u;
        }
        wsums[t] = r;  // inclusive
    }
    __syncthreads();
    const unsigned int binoff = ((wid ? wsums[wid - 1] : 0u) + q) - bs;  // exclusive
    cur[t] = binoff + gh[(size_t)t * BSORT + b];
    if (b == 0) binoffG[t] = binoff;  // publish for the aggregate
    __syncthreads();

    const int4* s4 = (const int4*)(src + b * SORT_CHUNK);
    const int4* d4 = (const int4*)(dst + b * SORT_CHUNK);
    for (int i = t; i < SORT_CHUNK / 4; i += 1024) {
        int4 s = s4[i];
        int4 d = d4[i];
        unsigned int p0 = atomicAdd(&cur[d.x >> 6], 1u);
        keysB[p0] = ((unsigned int)d.x << 16) | (unsigned int)s.x;
        unsigned int p1 = atomicAdd(&cur[d.y >> 6], 1u);
        keysB[p1] = ((unsigned int)d.y << 16) | (unsigned int)s.y;
        unsigned int p2 = atomicAdd(&cur[d.z >> 6], 1u);
        keysB[p2] = ((unsigned int)d.z << 16) | (unsigned int)s.z;
        unsigned int p3 = atomicAdd(&cur[d.w >> 6], 1u);
        keysB[p3] = ((unsigned int)d.w << 16) | (unsigned int)s.w;
    }
}

// ---------- Kernel 4: block per bucket (64 nodes), 512 threads (8 waves) ----------
__global__ __launch_bounds__(512)
void bucket_aggregate_kernel(const float* __restrict__ x,
                             const unsigned int* __restrict__ binoffG,
                             const unsigned int* __restrict__ keysB, const float* __restrict__ rs,
                             float* __restrict__ h) {
    __shared__ unsigned int ebuf[AGG_CAP];  // 12 KB
    __shared__ unsigned int ecnt[64];
    __shared__ unsigned int eoff[65];
    const int g = blockIdx.x;
    const int t = threadIdx.x;
    const int lane = t & 63;
    const int w = t >> 6;                  // 0..7
    const unsigned int base = binoffG[g];
    const unsigned int end  = (g + 1 < NBINS) ? binoffG[g + 1] : (unsigned int)N_EDGES;
    const int cnt = (int)(end - base);

    if (cnt > 0 && cnt <= AGG_CAP) {  // block-uniform branch
        if (t < 64) ecnt[t] = 0;
        __syncthreads();
        for (int i = t; i < cnt; i += 512) atomicAdd(&ecnt[(keysB[base + i] >> 16) & 63], 1u);
        __syncthreads();
        if (t < 64) {  // wave-0 shfl scan of 64 bin counts
            unsigned int c = ecnt[t];
            unsigned int q = c;
            for (int off = 1; off < 64; off <<= 1) {
                unsigned int u = __shfl_up(q, off, 64);
                if (lane >= off) q += u;
            }
            eoff[t] = q - c;          // exclusive
            if (t == 63) eoff[64] = q;
        }
        __syncthreads();
        if (t < 64) ecnt[t] = eoff[t];  // reuse as cursors
        __syncthreads();
        for (int i = t; i < cnt; i += 512) {
            unsigned int k = keysB[base + i];
            ebuf[atomicAdd(&ecnt[(k >> 16) & 63], 1u)] = k;
        }
        __syncthreads();

        const int grp = lane >> 4;   // edge sub-group 0..3
        const int fl  = lane & 15;   // float4 slot within the 64-feature row
        for (int nl = w; nl < 64; nl += 8) {
            int node = g * 64 + nl;
            if (node >= N_NODES) continue;
            const int jb = (int)eoff[nl];
            const int m  = (int)eoff[nl + 1] - jb;
            float ax = 0.0f, ay = 0.0f, az = 0.0f, aw = 0.0f;
            int jj = 0;
            // main: 8 edges per iteration (2 x dwordx4 in flight per wave)
            for (; jj + 8 <= m; jj += 8) {
                unsigned int s0 = ebuf[jb + jj + grp] & 0xFFFFu;
                unsigned int s1 = ebuf[jb + jj + 4 + grp] & 0xFFFFu;
                const float4 v0 = *(const float4*)&x[(size_t)s0 * D_FEAT + fl * 4];
                const float4 v1 = *(const float4*)&x[(size_t)s1 * D_FEAT + fl * 4];
                float w0 = rs[s0], w1 = rs[s1];
                ax = fmaf(v0.x, w0, ax); ay = fmaf(v0.y, w0, ay);
                az = fmaf(v0.z, w0, az); aw = fmaf(v0.w, w0, aw);
                ax = fmaf(v1.x, w1, ax); ay = fmaf(v1.y, w1, ay);
                az = fmaf(v1.z, w1, az); aw = fmaf(v1.w, w1, aw);
            }
            // tail: up to 7 edges, two masked groups-of-4
            if (jj < m) {
                int idx = jj + grp;
                unsigned int s = ebuf[jb + min(idx, m - 1)] & 0xFFFFu;
                float wgt = (idx < m) ? rs[s] : 0.0f;
                const float4 v = *(const float4*)&x[(size_t)s * D_FEAT + fl * 4];
                ax = fmaf(v.x, wgt, ax); ay = fmaf(v.y, wgt, ay);
                az = fmaf(v.z, wgt, az); aw = fmaf(v.w, wgt, aw);
                jj += 4;
                if (jj < m) {
                    idx = jj + grp;
                    unsigned int s2 = ebuf[jb + min(idx, m - 1)] & 0xFFFFu;
                    float wgt2 = (idx < m) ? rs[s2] : 0.0f;
                    const float4 v2 = *(const float4*)&x[(size_t)s2 * D_FEAT + fl * 4];
                    ax = fmaf(v2.x, wgt2, ax); ay = fmaf(v2.y, wgt2, ay);
                    az = fmaf(v2.z, wgt2, az); aw = fmaf(v2.w, wgt2, aw);
                }
            }
            // combine the 4 edge sub-groups: lanes l, l^16, l^32
            ax += __shfl_xor(ax, 16, 64); ay += __shfl_xor(ay, 16, 64);
            az += __shfl_xor(az, 16, 64); aw += __shfl_xor(aw, 16, 64);
            ax += __shfl_xor(ax, 32, 64); ay += __shfl_xor(ay, 32, 64);
            az += __shfl_xor(az, 32, 64); aw += __shfl_xor(aw, 32, 64);
            if (lane < 16) {
                float4 o;
                if (m > 0) {
                    const float rsn = rs[node];
                    o.x = ax * rsn; o.y = ay * rsn; o.z = az * rsn; o.w = aw * rsn;
                } else {
                    o.x = o.y = o.z = o.w = 0.0f;  // avoid 0*inf for deg-0 nodes
                }
                *(float4*)&h[(size_t)node * D_FEAT + fl * 4] = o;
            }
        }
    } else {
        // cnt == 0 (write zeros) or pathological overflow: filter directly from global.
        for (int nl = w; nl < 64; nl += 8) {
            int node = g * 64 + nl;
            if (node >= N_NODES) continue;
            float acc = 0.0f;
            int any = 0;
            for (unsigned int j = base; j < end; ++j) {
                unsigned int k = keysB[j];
                if ((int)((k >> 16) & 63) == nl) {
                    unsigned int s = k & 0xFFFFu;
                    acc = fmaf(x[(size_t)s * D_FEAT + lane], rs[s], acc);
                    any = 1;
                }
            }
            h[(size_t)node * D_FEAT + lane] = any ? acc * rs[node] : 0.0f;
        }
    }
}

// ---------- Fallback (tiny ws): atomic scatter ----------
__global__ void fb_degree_kernel(const int* __restrict__ src, unsigned int* __restrict__ deg,
                                 int n_edges) {
    int i = blockIdx.x * blockDim.x + threadIdx.x;
    int stride = gridDim.x * blockDim.x;
    for (; i < n_edges; i += stride) atomicAdd(&deg[src[i]], 1u);
}
__global__ void fb_scatter_kernel(const float* __restrict__ x, const int* __restrict__ src,
                                  const int* __restrict__ dst, const unsigned int* __restrict__ deg,
                                  float* __restrict__ h, int n_edges) {
    const int lane = threadIdx.x & 63;
    const int wave = (int)((blockIdx.x * blockDim.x + threadIdx.x) >> 6);
    const int nwaves = (int)((gridDim.x * blockDim.x) >> 6);
    for (int e = wave; e < n_edges; e += nwaves) {
        int s = __builtin_amdgcn_readfirstlane(src[e]);
        int d = __builtin_amdgcn_readfirstlane(dst[e]);
        float norm = rsqrtf((float)deg[s] * (float)deg[d]);
        atomicAdd(&h[d * D_FEAT + lane], x[s * D_FEAT + lane] * norm);
    }
}

// ---------- launch ----------
extern "C" void kernel_launch(void* const* d_in, const int* in_sizes, int n_in,
                              void* d_out, int out_size, void* d_ws, size_t ws_size,
                              hipStream_t stream) {
    const float* x   = (const float*)d_in[0];
    const int*   src = (const int*)d_in[1];
    const int*   dst = (const int*)d_in[2];
    float* h = (float*)d_out;

    // Workspace layout (~4.25 MB):
    //   keysB   : N_EDGES u32 (3.2 MB) -- aliased with hp32 (64*12500 u32 = 3.2 MB);
    //             hp8 fully consumed by binscan_rs before bucket_scatter writes keysB.
    //   gh      : NSCAN u32 (0.82 MB)
    //   rs      : N_NODES f32 (200 KB)
    //   binsum  : NBINS u32
    //   binoffG : NBINS u32
    size_t off = 0;
    unsigned int*  keysB   = (unsigned int*)((char*)d_ws + off);  off += (size_t)N_EDGES * 4;
    unsigned int*  hp32    = keysB;
    unsigned int*  gh      = (unsigned int*)((char*)d_ws + off);  off += (size_t)NSCAN * 4;
    float*         rs      = (float*)((char*)d_ws + off);         off += (size_t)N_NODES * 4;
    unsigned int*  binsum  = (unsigned int*)((char*)d_ws + off);  off += NBINS * 4;
    unsigned int*  binoffG = (unsigned int*)((char*)d_ws + off);  off += NBINS * 4;

    if (ws_size >= off) {
        // No memsets: every workspace/output element is fully overwritten.
        hist_count_kernel<<<dim3(HCHUNKS + BSORT), dim3(512), 0, stream>>>(src, dst, hp32, gh);
        binscan_rs_kernel<<<dim3(BINSCAN_BLOCKS + RS_BLOCKS), dim3(1024), 0, stream>>>(
            gh, binsum, (const unsigned char*)hp32, rs);
        bucket_scatter_kernel<<<dim3(BSORT), dim3(1024), 0, stream>>>(src, dst, gh, binsum,
                                                                      binoffG, keysB);
        bucket_aggregate_kernel<<<dim3(NAGG), dim3(512), 0, stream>>>(x, binoffG, keysB, rs, h);
    } else {
        // Fallback: atomic scatter (any ws >= 200 KB).
        unsigned int* deg = (unsigned int*)d_ws;
        hipMemsetAsync(deg, 0, N_NODES * sizeof(unsigned int), stream);
        hipMemsetAsync(d_out, 0, (size_t)out_size * sizeof(float), stream);
        fb_degree_kernel<<<dim3(1024), dim3(256), 0, stream>>>(src, deg, N_EDGES);
        fb_scatter_kernel<<<dim3(2048), dim3(256), 0, stream>>>(x, src, dst, deg, h, N_EDGES);
    }
}